// Round 1
// 578.455 us; speedup vs baseline: 1.0309x; 1.0309x over previous
//
#include <hip/hip_runtime.h>
#include <hip/hip_bf16.h>
#include <math.h>

typedef __attribute__((ext_vector_type(8))) short bf16x8;     // 8 bf16 = 4 VGPRs
typedef __attribute__((ext_vector_type(4))) float f32x4;      // MFMA accumulator
typedef __attribute__((ext_vector_type(8))) unsigned short u16x8;

typedef const float* fptr;
typedef const unsigned short* bfp;

__device__ inline float b2f(unsigned short u) {
    union { unsigned int i; float f; } v; v.i = ((unsigned int)u) << 16; return v.f;
}
__device__ inline unsigned short f2b(float x) {
    __hip_bfloat16 h = __float2bfloat16(x);
    return *(unsigned short*)&h;
}
// fast elu: __expf -> v_exp_f32 sequence; |err| ~1e-7 absolute near 0, fine for bf16-level outputs
__device__ inline float elu_f(float x) { return x > 0.f ? x : __expf(x) - 1.f; }

// async global->LDS, 16 bytes per lane; lds dest = wave-uniform base + lane*16
__device__ inline void load_lds16(const void* g, void* l) {
    __builtin_amdgcn_global_load_lds(
        (const __attribute__((address_space(1))) unsigned int*)g,
        (__attribute__((address_space(3))) unsigned int*)l, 16, 0, 0);
}

// ---------------------------------------------------------------------------
// Kernel 0 (MERGED PREP): one dispatch, grid 33537, blockIdx-partitioned.
// R8: latency-bound small blocks moved to the FRONT of the grid so their
// runtime hides under the 384 MB conversion stream instead of being a tail:
//   0               Wbt = Wb^T (bf16 [mid][d])
//   [1, 257)        small in_proj (query->qws, value1->v1ws)
//   [257, 769)      transpose+convert Wk/Wv2 -> WtK/WtV2 (bf16 [n][k])
//   [769, 33537)    convert key/value2 fp32 -> bf16 (AbfK / AbfV2)
// ---------------------------------------------------------------------------
__global__ __launch_bounds__(256) void prep(
    fptr key, fptr value2, unsigned short* AbfK, unsigned short* AbfV2,
    fptr Wk, fptr Wv2, unsigned short* WtK, unsigned short* WtV2,
    fptr Wb, unsigned short* Wbt,
    fptr query, fptr Wq, fptr bq, fptr gq, fptr Bq,
    fptr value1, fptr Wv1, fptr bv1, fptr gv1, fptr Bv1,
    float* qws, float* v1ws)
{
    __shared__ __align__(16) char smem[16640];
    int blk = blockIdx.x, t = threadIdx.x;

    if (blk == 0) {                          // ---- Wbt
        unsigned short* tb = (unsigned short*)smem;
        for (int i = 0; i < 32; i++) {
            int idx = i * 256 + t;           // idx = d*64 + mid
            tb[(idx & 63) * 128 + (idx >> 6)] = f2b(Wb[idx]);
        }
        __syncthreads();
        for (int i = 0; i < 4; i++) {
            int o = (i * 256 + t) * 8;
            *(u16x8*)&Wbt[o] = *(const u16x8*)&tb[o];
        }
        return;
    }
    if (blk < 257) {                         // ---- small_proj
        float* xs = (float*)smem;                      // 1024 f32
        float (*part)[128] = (float (*)[128])(smem + 4096);
        float (*r4)[2] = (float (*)[2])(smem + 4096 + 1024);
        int idx = blk - 1;
        int hgrp = idx & 7;
        int row  = (idx >> 3) & 15;
        int which = idx >> 7;
        fptr x  = which ? value1 : query;
        fptr W  = which ? Wv1 : Wq;
        fptr bi = which ? bv1 : bq;
        fptr g  = which ? gv1 : gq;
        fptr be = which ? Bv1 : Bq;
        float* outp = which ? v1ws : qws;
        int lane = t & 63, wv = t >> 6;
        for (int i = t; i < 1024; i += 256) xs[i] = x[row * 1024 + i];
        __syncthreads();
        int cl = t & 127, kh = t >> 7;
        int col = hgrp * 128 + cl;
        float acc = 0.f;
        const float* wp = W + (size_t)(kh * 512) * 1024 + col;
        for (int k = 0; k < 512; k++) acc += xs[kh * 512 + k] * wp[(size_t)k * 1024];
        part[kh][cl] = acc;
        __syncthreads();
        float e = 0.f;
        if (t < 128) e = elu_f(part[0][t] + part[1][t] + bi[col]);
        float s = e, ss = e * e;
        for (int m = 32; m > 0; m >>= 1) { s += __shfl_xor(s, m); ss += __shfl_xor(ss, m); }
        if (lane == 0) { r4[wv][0] = s; r4[wv][1] = ss; }
        __syncthreads();
        float S  = r4[0][0] + r4[1][0] + r4[2][0] + r4[3][0];
        float SS = r4[0][1] + r4[1][1] + r4[2][1] + r4[3][1];
        float mean = S * (1.f / 128.f);
        float var  = SS * (1.f / 128.f) - mean * mean;
        float inv  = rsqrtf(var + 1e-3f);
        if (t < 128) outp[row * 1024 + col] = (e - mean) * inv * g[col] + be[col];
        return;
    }
    if (blk < 769) {                         // ---- convert_w (transpose)
        float (*tl)[65] = (float (*)[65])smem;
        int idx = blk - 257;
        fptr W = (idx >> 8) ? Wv2 : Wk;
        unsigned short* Wt = (idx >> 8) ? WtV2 : WtK;
        int k0 = ((idx >> 4) & 15) * 64, n0 = (idx & 15) * 64;
        #pragma unroll
        for (int i = 0; i < 16; i++) {
            int kl = i * 4 + (t >> 6), nl = t & 63;
            tl[kl][nl] = W[(size_t)(k0 + kl) * 1024 + n0 + nl];
        }
        __syncthreads();
        #pragma unroll
        for (int i = 0; i < 16; i++) {
            int nl = i * 4 + (t >> 6), kl = t & 63;
            Wt[(size_t)(n0 + nl) * 1024 + k0 + kl] = f2b(tl[kl][nl]);
        }
        return;
    }
    {                                        // ---- convert_a2
        int idx = blk - 769;
        fptr A = (idx < 16384) ? key : value2;
        unsigned short* B = (idx < 16384) ? AbfK : AbfV2;
        size_t e = ((size_t)(idx & 16383) * 256 + t) * 8;
        const float4* ap = (const float4*)(A + e);
        float4 a0 = ap[0], a1 = ap[1];
        u16x8 p = { f2b(a0.x), f2b(a0.y), f2b(a0.z), f2b(a0.w),
                    f2b(a1.x), f2b(a1.y), f2b(a1.z), f2b(a1.w) };
        *(u16x8*)(B + e) = p;
    }
}

// ---------------------------------------------------------------------------
// Kernel 2: BOTH big GEMMs in one dispatch. grid(4096), block 256.
// R8 A-LOCALITY DECODE: consecutive blocks round-robin XCDs, so we decode
//   xcd = bid & 7, seq = bid >> 3 (per-XCD issue order),
//   grp = seq >> 3 (A row-panel group), h = seq & 7,
//   which = grp >> 5 (each XCD does all its K-gemm panels, then V2),
//   rowtile = xcd * 32 + (grp & 31).
// => the 8 h-blocks that read the SAME 256 KB A panel run back-to-back on
// the SAME XCD; weight working set per XCD is 2 MB (one which at a time).
// Predicted: FETCH_SIZE 541 MB -> ~300 MB; staging becomes L2-hit ->
// shorter vmcnt(0) drain at the K-step barrier -> MfmaUtil 25% -> 31-35%.
// K-loop: m97 staging, BK=64 dbuf panels (verified R5-R7).
// Epilogue: bias+elu+groupnorm (verified); which==0 adds attn MFMA phase,
// with the qwb B-operand now computed in-register from Wbt*q (qwb_prep gone).
// __launch_bounds__(256,3): 3 blocks/CU (verified R7: occupancy 32%).
// ---------------------------------------------------------------------------
__global__ __launch_bounds__(256, 3) void gemm_fused(
    bfp AK, bfp WtK, fptr bkp, fptr gkp, fptr Bkp,
    bfp AV, bfp WtV, fptr bvp, fptr gvp, fptr Bvp,
    bfp Wbt, const float* qws, fptr maskp, fptr bbp, fptr Wl1, fptr bl1,
    float* logits, float* poolpart, __hip_bfloat16* Z)
{
    __shared__ __align__(16) unsigned short pool[17408];
    unsigned short (*As)[128][32] = (unsigned short (*)[128][32])pool;
    unsigned short (*Bs)[128][32] = (unsigned short (*)[128][32])(pool + 8192);
    unsigned short (*Tt)[136]     = (unsigned short (*)[136])pool;
    __shared__ float sstat[128][2][2];
    __shared__ float masksh[128];
    __shared__ float poolred[4][64];

    int bid = blockIdx.x;
    int xcd = bid & 7;
    int seq = bid >> 3;              // per-XCD issue order 0..511
    int grp = seq >> 3;              // 0..63: A-panel group
    int h   = seq & 7;               // all 8 h of a panel adjacent on one XCD
    int which = grp >> 5;            // K-gemm phase, then V2-gemm phase
    int rowtile = xcd * 32 + (grp & 31);   // 0..255

    int r0 = rowtile * 128;          // global row (b*2048 + mloc)
    int n0 = h * 128;
    int b  = r0 >> 11;
    int mloc = r0 & 2047;
    int mt = rowtile & 15;
    int t = threadIdx.x, lane = t & 63, w = t >> 6;
    int c = lane & 15, q = lane >> 4;
    int rowbase = (w & 1) * 64, colbase = (w >> 1) * 64;

    bfp A    = which ? AV  : AK;
    bfp Wt   = which ? WtV : WtK;
    fptr bias = which ? bvp : bkp;
    fptr g    = which ? gvp : gkp;
    fptr be   = which ? Bvp : Bkp;

    if (which == 0 && t < 128) masksh[t] = maskp[r0 + t];

    f32x4 acc[4][4];
    const f32x4 fzero = {0.f, 0.f, 0.f, 0.f};
    #pragma unroll
    for (int i = 0; i < 4; i++)
        #pragma unroll
        for (int j = 0; j < 4; j++) acc[i][j] = fzero;

    int srow = lane >> 2;            // 0..15 within a 16-row issue
    int sseg = (lane & 3) * 8;       // k offset (8 bf16 = 16 B)
    const unsigned short* ag = A  + (size_t)(r0 + w * 32 + srow) * 1024 + sseg;
    const unsigned short* bg = Wt + (size_t)(n0 + w * 32 + srow) * 1024 + sseg;

    for (int k0 = 0; k0 < 1024; k0 += 64) {
        load_lds16(ag + k0,                  &As[0][w * 32][0]);
        load_lds16(ag + k0 + 16 * 1024,      &As[0][w * 32 + 16][0]);
        load_lds16(ag + k0 + 32,             &As[1][w * 32][0]);
        load_lds16(ag + k0 + 32 + 16 * 1024, &As[1][w * 32 + 16][0]);
        load_lds16(bg + k0,                  &Bs[0][w * 32][0]);
        load_lds16(bg + k0 + 16 * 1024,      &Bs[0][w * 32 + 16][0]);
        load_lds16(bg + k0 + 32,             &Bs[1][w * 32][0]);
        load_lds16(bg + k0 + 32 + 16 * 1024, &Bs[1][w * 32 + 16][0]);
        __syncthreads();
        #pragma unroll
        for (int p = 0; p < 2; p++) {
            bf16x8 af[4], bfv[4];
            #pragma unroll
            for (int i = 0; i < 4; i++) af[i]  = *(const bf16x8*)&As[p][rowbase + i * 16 + c][q * 8];
            #pragma unroll
            for (int j = 0; j < 4; j++) bfv[j] = *(const bf16x8*)&Bs[p][colbase + j * 16 + c][q * 8];
            #pragma unroll
            for (int i = 0; i < 4; i++)
                #pragma unroll
                for (int j = 0; j < 4; j++)
                    acc[i][j] = __builtin_amdgcn_mfma_f32_16x16x32_bf16(af[i], bfv[j], acc[i][j], 0, 0, 0);
        }
        __syncthreads();
    }

    // ---- bias + elu + groupnorm stats (verified epilogue)
    float bcol[4], gcol[4], Bcol[4];
    #pragma unroll
    for (int j = 0; j < 4; j++) {
        int cg = n0 + colbase + j * 16 + c;
        bcol[j] = bias[cg]; gcol[j] = g[cg]; Bcol[j] = be[cg];
    }
    #pragma unroll
    for (int i = 0; i < 4; i++)
        #pragma unroll
        for (int j = 0; j < 4; j++)
            #pragma unroll
            for (int r = 0; r < 4; r++)
                acc[i][j][r] = elu_f(acc[i][j][r] + bcol[j]);
    #pragma unroll
    for (int i = 0; i < 4; i++) {
        #pragma unroll
        for (int r = 0; r < 4; r++) {
            float s  = acc[i][0][r] + acc[i][1][r] + acc[i][2][r] + acc[i][3][r];
            float ss = acc[i][0][r] * acc[i][0][r] + acc[i][1][r] * acc[i][1][r]
                     + acc[i][2][r] * acc[i][2][r] + acc[i][3][r] * acc[i][3][r];
            for (int m = 1; m < 16; m <<= 1) { s += __shfl_xor(s, m); ss += __shfl_xor(ss, m); }
            if (c == 0) {
                int rl = rowbase + i * 16 + q * 4 + r;
                sstat[rl][w >> 1][0] = s;
                sstat[rl][w >> 1][1] = ss;
            }
        }
    }
    __syncthreads();
    // normalize; which==0 -> Tt (LDS, staging space dead), which==1 -> Z
    #pragma unroll
    for (int i = 0; i < 4; i++) {
        #pragma unroll
        for (int r = 0; r < 4; r++) {
            int rl = rowbase + i * 16 + q * 4 + r;
            float S  = sstat[rl][0][0] + sstat[rl][1][0];
            float SS = sstat[rl][0][1] + sstat[rl][1][1];
            float mean = S * (1.f / 128.f);
            float var  = SS * (1.f / 128.f) - mean * mean;
            float inv  = rsqrtf(var + 1e-3f);
            #pragma unroll
            for (int j = 0; j < 4; j++) {
                int cl = colbase + j * 16 + c;
                float v = (acc[i][j][r] - mean) * inv * gcol[j] + Bcol[j];
                if (which == 0) Tt[rl][cl] = f2b(v);
                else Z[(size_t)(r0 + rl) * 1024 + n0 + cl] = __float2bfloat16(v);
            }
        }
    }
    if (which != 0) return;
    __syncthreads();

    // ---- attn phase (verified R6/R7): basic = relu(Tt @ (Wbt*q)^T + bb)
    // R8: B-operand fragments computed in-register from Wbt (bf16 [mid][d],
    // L2-hot 16 KB) and q (f32, 64 KB) -- identical arithmetic to the old
    // qwb_prep kernel (bf16 round of Wbt_bf16 * q_f32), which is now deleted.
    const float* qrow = qws + b * 1024 + h * 128;
    f32x4 acc2[2][4];
    #pragma unroll
    for (int i = 0; i < 2; i++)
        #pragma unroll
        for (int j = 0; j < 4; j++) acc2[i][j] = fzero;
    #pragma unroll
    for (int s = 0; s < 4; s++) {
        bf16x8 af2[2], bfv[4];
        float qv[8];
        #pragma unroll
        for (int e = 0; e < 8; e++) qv[e] = qrow[s * 32 + q * 8 + e];
        #pragma unroll
        for (int i = 0; i < 2; i++)
            af2[i] = *(const bf16x8*)&Tt[w * 32 + i * 16 + c][s * 32 + q * 8];
        #pragma unroll
        for (int j = 0; j < 4; j++) {
            bf16x8 wv = *(const bf16x8*)&Wbt[(j * 16 + c) * 128 + s * 32 + q * 8];
            bf16x8 bv;
            #pragma unroll
            for (int e = 0; e < 8; e++)
                bv[e] = (short)f2b(b2f((unsigned short)wv[e]) * qv[e]);
            bfv[j] = bv;
        }
        #pragma unroll
        for (int i = 0; i < 2; i++)
            #pragma unroll
            for (int j = 0; j < 4; j++)
                acc2[i][j] = __builtin_amdgcn_mfma_f32_16x16x32_bf16(af2[i], bfv[j], acc2[i][j], 0, 0, 0);
    }

    float bbs[4], wl1s[4];
    #pragma unroll
    for (int j = 0; j < 4; j++) { bbs[j] = bbp[j * 16 + c]; wl1s[j] = Wl1[j * 16 + c]; }
    float bl1v = bl1[0];
    float pp[4] = {0.f, 0.f, 0.f, 0.f};
    #pragma unroll
    for (int i = 0; i < 2; i++) {
        #pragma unroll
        for (int r = 0; r < 4; r++) {
            int ml = w * 32 + i * 16 + q * 4 + r;
            float mv = masksh[ml];
            float lg = 0.f;
            #pragma unroll
            for (int j = 0; j < 4; j++) {
                float basic = fmaxf(acc2[i][j][r] + bbs[j], 0.f);
                lg += basic * wl1s[j];
                pp[j] += basic * mv;
            }
            lg += __shfl_xor(lg, 1); lg += __shfl_xor(lg, 2);
            lg += __shfl_xor(lg, 4); lg += __shfl_xor(lg, 8);
            if (c == 0)
                logits[((size_t)(b * 8 + h)) * 2048 + mloc + ml] = lg + bl1v;
        }
    }
    #pragma unroll
    for (int j = 0; j < 4; j++) {
        pp[j] += __shfl_xor(pp[j], 16);
        pp[j] += __shfl_xor(pp[j], 32);
    }
    if (lane < 16) {
        #pragma unroll
        for (int j = 0; j < 4; j++) poolred[w][j * 16 + c] = pp[j];
    }
    __syncthreads();
    if (t < 64) {
        float p = poolred[0][t] + poolred[1][t] + poolred[2][t] + poolred[3][t];
        poolpart[((size_t)((b * 8 + h) * 16 + mt)) * 64 + t] = p;
    }
}

// ---------------------------------------------------------------------------
// Kernel 3: FUSED softmax + pool + alpha_ch + v2 aggregation + output.
// grid (h=8, b=16), block 512 (8 waves: 2x latency hiding on the v2 read).
// ---------------------------------------------------------------------------
__global__ __launch_bounds__(512) void finalize_fused(
    const float* logits, const float* poolpart, fptr maskp,
    const __hip_bfloat16* v2buf, const float* v1ws,
    fptr Wl2, fptr bl2, float* out)
{
    __shared__ float alph[2048];
    __shared__ float red[8];
    __shared__ float redm[8];
    __shared__ float pools[64];
    __shared__ float ach[128];
    __shared__ float redl[8][128];
    int h = blockIdx.x, b = blockIdx.y;
    int t = threadIdx.x, lane = t & 63, wv = t >> 6;

    const float* lg = logits + (size_t)(b * 8 + h) * 2048;
    float msum_l = 0.f, mx_l = -1e30f;
    for (int i = t; i < 2048; i += 512) {
        float mv = maskp[b * 2048 + i];
        msum_l += mv;
        float v = (mv == 0.f) ? -1e9f : lg[i];
        alph[i] = v;
        mx_l = fmaxf(mx_l, v);
    }
    for (int mm = 32; mm > 0; mm >>= 1) {
        msum_l += __shfl_xor(msum_l, mm);
        mx_l = fmaxf(mx_l, __shfl_xor(mx_l, mm));
    }
    if (lane == 0) { red[wv] = msum_l; redm[wv] = mx_l; }
    __syncthreads();
    float msum = 0.f, mx = -1e30f;
    #pragma unroll
    for (int i = 0; i < 8; i++) { msum += red[i]; mx = fmaxf(mx, redm[i]); }

    float se = 0.f;
    for (int i = t; i < 2048; i += 512) {
        float e = __expf(alph[i] - mx);   // same thread wrote alph[i]
        alph[i] = e;
        se += e;
    }
    for (int mm = 32; mm > 0; mm >>= 1) se += __shfl_xor(se, mm);
    __syncthreads();
    if (lane == 0) red[wv] = se;
    __syncthreads();
    float S = 0.f;
    #pragma unroll
    for (int i = 0; i < 8; i++) S += red[i];
    float invS = 1.f / S;
    for (int i = t; i < 2048; i += 512) alph[i] *= invS;

    if (t < 64) {
        const float* pq = poolpart + ((size_t)(b * 8 + h) * 16) * 64 + t;
        float p = 0.f;
        for (int pt = 0; pt < 16; pt++) p += pq[pt * 64];
        pools[t] = p / msum;
    }
    __syncthreads();
    if (t < 128) {
        float s2 = bl2[t];
        for (int mid = 0; mid < 64; mid++) s2 += pools[mid] * Wl2[mid * 128 + t];
        ach[t] = 1.f / (1.f + __expf(-s2));
    }
    __syncthreads();

    // v2 aggregation over 2048 m: 8 waves x 4 m-rows per iter = 32 m/iter
    int mo = lane >> 4, d8 = (lane & 15) * 8;
    float acc[8] = {};
    for (int it = 0; it < 64; it++) {
        int m = it * 32 + wv * 4 + mo;
        bf16x8 v8 = *(const bf16x8*)&v2buf[((size_t)(b * 2048 + m)) * 1024 + h * 128 + d8];
        float a = alph[m];
        #pragma unroll
        for (int j = 0; j < 8; j++)
            acc[j] += a * b2f(((unsigned short*)&v8)[j]);
    }
    #pragma unroll
    for (int j = 0; j < 8; j++) {
        acc[j] += __shfl_xor(acc[j], 16);
        acc[j] += __shfl_xor(acc[j], 32);
    }
    if (lane < 16) {
        #pragma unroll
        for (int j = 0; j < 8; j++) redl[wv][d8 + j] = acc[j];
    }
    __syncthreads();
    if (t < 128) {
        float s = 0.f;
        #pragma unroll
        for (int i = 0; i < 8; i++) s += redl[i][t];
        out[b * 1024 + h * 128 + t] = v1ws[b * 1024 + h * 128 + t] * s * ach[t];
    }
}

// ---------------------------------------------------------------------------
extern "C" void kernel_launch(void* const* d_in, const int* in_sizes, int n_in,
                              void* d_out, int out_size, void* d_ws, size_t ws_size,
                              hipStream_t stream) {
    fptr query  = (fptr)d_in[0];
    fptr key    = (fptr)d_in[1];
    fptr maskp  = (fptr)d_in[2];
    fptr value1 = (fptr)d_in[3];
    fptr value2 = (fptr)d_in[4];
    fptr Wq = (fptr)d_in[5],  bq = (fptr)d_in[6],  gq = (fptr)d_in[7],  Bq = (fptr)d_in[8];
    fptr Wk = (fptr)d_in[9],  bk = (fptr)d_in[10], gk = (fptr)d_in[11], Bk = (fptr)d_in[12];
    fptr Wv1 = (fptr)d_in[13], bv1 = (fptr)d_in[14], gv1 = (fptr)d_in[15], Bv1 = (fptr)d_in[16];
    fptr Wv2 = (fptr)d_in[17], bv2 = (fptr)d_in[18], gv2 = (fptr)d_in[19], Bv2 = (fptr)d_in[20];
    fptr Wb = (fptr)d_in[21], bb = (fptr)d_in[22];
    fptr Wl1 = (fptr)d_in[23], bl1 = (fptr)d_in[24];
    fptr Wl2 = (fptr)d_in[25], bl2 = (fptr)d_in[26];

    const size_t MB = 1024 * 1024;
    char* w = (char*)d_ws;
    unsigned short* AbfK  = (unsigned short*)w;                      // 0..64 MB
    unsigned short* AbfV2 = (unsigned short*)(w + 64 * MB);          // 64..128 MB
    __hip_bfloat16* zV2   = (__hip_bfloat16*)(w + 128 * MB);         // 128..192 MB
    unsigned short* WtK   = (unsigned short*)(w + 192 * MB);         // 2 MB
    unsigned short* WtV2  = (unsigned short*)(w + 194 * MB);         // 2 MB
    unsigned short* Wbt   = (unsigned short*)(w + 196 * MB);         // 16 KB
    float* qws      = (float*)(w + 196 * MB + 65536 + 2 * MB);       // 64 KB (qwbuf slot now unused)
    float* v1ws     = qws + 16 * 1024;                               // 64 KB
    float* logits   = v1ws + 16 * 1024;                              // 1 MB
    float* poolpart = logits + 16 * 8 * 2048;                        // 512 KB (-> <200 MB total)
    float* out = (float*)d_out;

    hipLaunchKernelGGL(prep, dim3(33537), dim3(256), 0, stream,
                       key, value2, AbfK, AbfV2,
                       Wk, Wv2, WtK, WtV2, Wb, Wbt,
                       query, Wq, bq, gq, Bq, value1, Wv1, bv1, gv1, Bv1,
                       qws, v1ws);
    hipLaunchKernelGGL(gemm_fused, dim3(4096), dim3(256), 0, stream,
                       (bfp)AbfK, (bfp)WtK, bk, gk, Bk,
                       (bfp)AbfV2, (bfp)WtV2, bv2, gv2, Bv2,
                       (bfp)Wbt, qws, maskp, bb, Wl1, bl1, logits, poolpart, zV2);
    hipLaunchKernelGGL(finalize_fused, dim3(8, 16), dim3(512), 0, stream,
                       logits, poolpart, maskp, zV2, v1ws, Wl2, bl2, out);
}

// Round 3
// 565.737 us; speedup vs baseline: 1.0541x; 1.0225x over previous
//
#include <hip/hip_runtime.h>
#include <hip/hip_bf16.h>
#include <math.h>

typedef __attribute__((ext_vector_type(8))) short bf16x8;     // 8 bf16 = 4 VGPRs
typedef __attribute__((ext_vector_type(4))) float f32x4;      // MFMA accumulator
typedef __attribute__((ext_vector_type(8))) unsigned short u16x8;

typedef const float* fptr;
typedef const unsigned short* bfp;

__device__ inline float b2f(unsigned short u) {
    union { unsigned int i; float f; } v; v.i = ((unsigned int)u) << 16; return v.f;
}
__device__ inline unsigned short f2b(float x) {
    __hip_bfloat16 h = __float2bfloat16(x);
    return *(unsigned short*)&h;
}
// fast elu: __expf -> v_exp_f32 sequence; |err| ~1e-7 absolute near 0, fine for bf16-level outputs
__device__ inline float elu_f(float x) { return x > 0.f ? x : __expf(x) - 1.f; }

// async global->LDS, 16 bytes per lane; lds dest = wave-uniform base + lane*16
__device__ inline void load_lds16(const void* g, void* l) {
    __builtin_amdgcn_global_load_lds(
        (const __attribute__((address_space(1))) unsigned int*)g,
        (__attribute__((address_space(3))) unsigned int*)l, 16, 0, 0);
}

// ---------------------------------------------------------------------------
// Kernel 0 (MERGED PREP): one dispatch, grid 4865, blockIdx-partitioned.
// R9/R10: convert part grid-strided (G11) to cut block count 33537 -> 4865;
// transpose writes vectorized (u16x8, 16B/lane).
//   0               Wbt = Wb^T (bf16 [mid][d])
//   [1, 257)        small in_proj (query->qws, value1->v1ws)
//   [257, 769)      transpose+convert Wk/Wv2 -> WtK/WtV2 (bf16 [n][k])
//   [769, 4865)     convert key/value2 fp32 -> bf16 (AbfK / AbfV2), 8x strided
// ---------------------------------------------------------------------------
__global__ __launch_bounds__(256) void prep(
    fptr key, fptr value2, unsigned short* AbfK, unsigned short* AbfV2,
    fptr Wk, fptr Wv2, unsigned short* WtK, unsigned short* WtV2,
    fptr Wb, unsigned short* Wbt,
    fptr query, fptr Wq, fptr bq, fptr gq, fptr Bq,
    fptr value1, fptr Wv1, fptr bv1, fptr gv1, fptr Bv1,
    float* qws, float* v1ws)
{
    __shared__ __align__(16) char smem[16640];
    int blk = blockIdx.x, t = threadIdx.x;

    if (blk == 0) {                          // ---- Wbt
        unsigned short* tb = (unsigned short*)smem;
        for (int i = 0; i < 32; i++) {
            int idx = i * 256 + t;           // idx = d*64 + mid
            tb[(idx & 63) * 128 + (idx >> 6)] = f2b(Wb[idx]);
        }
        __syncthreads();
        for (int i = 0; i < 4; i++) {
            int o = (i * 256 + t) * 8;
            *(u16x8*)&Wbt[o] = *(const u16x8*)&tb[o];
        }
        return;
    }
    if (blk < 257) {                         // ---- small_proj
        float* xs = (float*)smem;                      // 1024 f32
        float (*part)[128] = (float (*)[128])(smem + 4096);
        float (*r4)[2] = (float (*)[2])(smem + 4096 + 1024);
        int idx = blk - 1;
        int hgrp = idx & 7;
        int row  = (idx >> 3) & 15;
        int which = idx >> 7;
        fptr x  = which ? value1 : query;
        fptr W  = which ? Wv1 : Wq;
        fptr bi = which ? bv1 : bq;
        fptr g  = which ? gv1 : gq;
        fptr be = which ? Bv1 : Bq;
        float* outp = which ? v1ws : qws;
        int lane = t & 63, wv = t >> 6;
        for (int i = t; i < 1024; i += 256) xs[i] = x[row * 1024 + i];
        __syncthreads();
        int cl = t & 127, kh = t >> 7;
        int col = hgrp * 128 + cl;
        float acc = 0.f;
        const float* wp = W + (size_t)(kh * 512) * 1024 + col;
        for (int k = 0; k < 512; k++) acc += xs[kh * 512 + k] * wp[(size_t)k * 1024];
        part[kh][cl] = acc;
        __syncthreads();
        float e = 0.f;
        if (t < 128) e = elu_f(part[0][t] + part[1][t] + bi[col]);
        float s = e, ss = e * e;
        for (int m = 32; m > 0; m >>= 1) { s += __shfl_xor(s, m); ss += __shfl_xor(ss, m); }
        if (lane == 0) { r4[wv][0] = s; r4[wv][1] = ss; }
        __syncthreads();
        float S  = r4[0][0] + r4[1][0] + r4[2][0] + r4[3][0];
        float SS = r4[0][1] + r4[1][1] + r4[2][1] + r4[3][1];
        float mean = S * (1.f / 128.f);
        float var  = SS * (1.f / 128.f) - mean * mean;
        float inv  = rsqrtf(var + 1e-3f);
        if (t < 128) outp[row * 1024 + col] = (e - mean) * inv * g[col] + be[col];
        return;
    }
    if (blk < 769) {                         // ---- convert_w (transpose)
        float (*tl)[65] = (float (*)[65])smem;
        int idx = blk - 257;
        fptr W = (idx >> 8) ? Wv2 : Wk;
        unsigned short* Wt = (idx >> 8) ? WtV2 : WtK;
        int k0 = ((idx >> 4) & 15) * 64, n0 = (idx & 15) * 64;
        #pragma unroll
        for (int i = 0; i < 16; i++) {
            int kl = i * 4 + (t >> 6), nl = t & 63;
            tl[kl][nl] = W[(size_t)(k0 + kl) * 1024 + n0 + nl];
        }
        __syncthreads();
        // vectorized write: 8 consecutive k per thread -> u16x8 (16B/lane)
        #pragma unroll
        for (int i = 0; i < 2; i++) {
            int nl = i * 32 + (t >> 3), kl8 = (t & 7) * 8;
            u16x8 o;
            #pragma unroll
            for (int e = 0; e < 8; e++) o[e] = f2b(tl[kl8 + e][nl]);
            *(u16x8*)&Wt[(size_t)(n0 + nl) * 1024 + k0 + kl8] = o;
        }
        return;
    }
    {                                        // ---- convert_a2, grid-strided x8
        int idx = blk - 769;                 // 0..4095
        fptr A = (idx < 2048) ? key : value2;
        unsigned short* Bp = (idx < 2048) ? AbfK : AbfV2;
        size_t base = (size_t)(idx & 2047) * 16384 + (size_t)t * 8;
        #pragma unroll
        for (int i = 0; i < 8; i++) {
            size_t e = base + (size_t)i * 2048;
            const float4* ap = (const float4*)(A + e);
            float4 a0 = ap[0], a1 = ap[1];
            u16x8 p = { f2b(a0.x), f2b(a0.y), f2b(a0.z), f2b(a0.w),
                        f2b(a1.x), f2b(a1.y), f2b(a1.z), f2b(a1.w) };
            *(u16x8*)(Bp + e) = p;
        }
    }
}

// ---------------------------------------------------------------------------
// Kernel 2: BOTH big GEMMs in one dispatch. grid(4096), block 256.
// R8 A-LOCALITY DECODE (verified: FETCH 541->115 MB): xcd = bid & 7,
// seq = bid >> 3, grp = seq >> 3, h = seq & 7, which = grp >> 5,
// rowtile = xcd * 32 + (grp & 31).
// R9/R10: __launch_bounds__(256,4) -- arch-VGPR was 68 + 64 AGPR = 132,
// 4 over the 128 cliff capping residency at 3 waves/SIMD. Forcing 64 arch
// VGPRs lets 4 blocks/CU co-reside (LDS 4*38400 = 150K fits 160K); barrier
// drains of one block overlap MFMA of three others (m114 mechanism; 2-phase
// stall is the bottleneck: MfmaUtil 25%, HBM 9.6%).
// R9/R10: which==1 Z-write routed through Tt LDS then stored u16x8.
// ---------------------------------------------------------------------------
__global__ __launch_bounds__(256, 4) void gemm_fused(
    bfp AK, bfp WtK, fptr bkp, fptr gkp, fptr Bkp,
    bfp AV, bfp WtV, fptr bvp, fptr gvp, fptr Bvp,
    bfp Wbt, const float* qws, fptr maskp, fptr bbp, fptr Wl1, fptr bl1,
    float* logits, float* poolpart, __hip_bfloat16* Z)
{
    __shared__ __align__(16) unsigned short pool[17408];
    unsigned short (*As)[128][32] = (unsigned short (*)[128][32])pool;
    unsigned short (*Bs)[128][32] = (unsigned short (*)[128][32])(pool + 8192);
    unsigned short (*Tt)[136]     = (unsigned short (*)[136])pool;
    __shared__ float sstat[128][2][2];
    __shared__ float masksh[128];
    __shared__ float poolred[4][64];

    int bid = blockIdx.x;
    int xcd = bid & 7;
    int seq = bid >> 3;              // per-XCD issue order 0..511
    int grp = seq >> 3;              // 0..63: A-panel group
    int h   = seq & 7;               // all 8 h of a panel adjacent on one XCD
    int which = grp >> 5;            // K-gemm phase, then V2-gemm phase
    int rowtile = xcd * 32 + (grp & 31);   // 0..255

    int r0 = rowtile * 128;          // global row (b*2048 + mloc)
    int n0 = h * 128;
    int b  = r0 >> 11;
    int mloc = r0 & 2047;
    int mt = rowtile & 15;
    int t = threadIdx.x, lane = t & 63, w = t >> 6;
    int c = lane & 15, q = lane >> 4;
    int rowbase = (w & 1) * 64, colbase = (w >> 1) * 64;

    bfp A    = which ? AV  : AK;
    bfp Wt   = which ? WtV : WtK;
    fptr bias = which ? bvp : bkp;
    fptr g    = which ? gvp : gkp;
    fptr be   = which ? Bvp : Bkp;

    if (which == 0 && t < 128) masksh[t] = maskp[r0 + t];

    f32x4 acc[4][4];
    const f32x4 fzero = {0.f, 0.f, 0.f, 0.f};
    #pragma unroll
    for (int i = 0; i < 4; i++)
        #pragma unroll
        for (int j = 0; j < 4; j++) acc[i][j] = fzero;

    int srow = lane >> 2;            // 0..15 within a 16-row issue
    int sseg = (lane & 3) * 8;       // k offset (8 bf16 = 16 B)
    const unsigned short* ag = A  + (size_t)(r0 + w * 32 + srow) * 1024 + sseg;
    const unsigned short* bg = Wt + (size_t)(n0 + w * 32 + srow) * 1024 + sseg;

    for (int k0 = 0; k0 < 1024; k0 += 64) {
        load_lds16(ag + k0,                  &As[0][w * 32][0]);
        load_lds16(ag + k0 + 16 * 1024,      &As[0][w * 32 + 16][0]);
        load_lds16(ag + k0 + 32,             &As[1][w * 32][0]);
        load_lds16(ag + k0 + 32 + 16 * 1024, &As[1][w * 32 + 16][0]);
        load_lds16(bg + k0,                  &Bs[0][w * 32][0]);
        load_lds16(bg + k0 + 16 * 1024,      &Bs[0][w * 32 + 16][0]);
        load_lds16(bg + k0 + 32,             &Bs[1][w * 32][0]);
        load_lds16(bg + k0 + 32 + 16 * 1024, &Bs[1][w * 32 + 16][0]);
        __syncthreads();
        #pragma unroll
        for (int p = 0; p < 2; p++) {
            bf16x8 af[4], bfv[4];
            #pragma unroll
            for (int i = 0; i < 4; i++) af[i]  = *(const bf16x8*)&As[p][rowbase + i * 16 + c][q * 8];
            #pragma unroll
            for (int j = 0; j < 4; j++) bfv[j] = *(const bf16x8*)&Bs[p][colbase + j * 16 + c][q * 8];
            #pragma unroll
            for (int i = 0; i < 4; i++)
                #pragma unroll
                for (int j = 0; j < 4; j++)
                    acc[i][j] = __builtin_amdgcn_mfma_f32_16x16x32_bf16(af[i], bfv[j], acc[i][j], 0, 0, 0);
        }
        __syncthreads();
    }

    // ---- bias + elu + groupnorm stats (verified epilogue)
    float bcol[4], gcol[4], Bcol[4];
    #pragma unroll
    for (int j = 0; j < 4; j++) {
        int cg = n0 + colbase + j * 16 + c;
        bcol[j] = bias[cg]; gcol[j] = g[cg]; Bcol[j] = be[cg];
    }
    #pragma unroll
    for (int i = 0; i < 4; i++)
        #pragma unroll
        for (int j = 0; j < 4; j++)
            #pragma unroll
            for (int r = 0; r < 4; r++)
                acc[i][j][r] = elu_f(acc[i][j][r] + bcol[j]);
    #pragma unroll
    for (int i = 0; i < 4; i++) {
        #pragma unroll
        for (int r = 0; r < 4; r++) {
            float s  = acc[i][0][r] + acc[i][1][r] + acc[i][2][r] + acc[i][3][r];
            float ss = acc[i][0][r] * acc[i][0][r] + acc[i][1][r] * acc[i][1][r]
                     + acc[i][2][r] * acc[i][2][r] + acc[i][3][r] * acc[i][3][r];
            for (int m = 1; m < 16; m <<= 1) { s += __shfl_xor(s, m); ss += __shfl_xor(ss, m); }
            if (c == 0) {
                int rl = rowbase + i * 16 + q * 4 + r;
                sstat[rl][w >> 1][0] = s;
                sstat[rl][w >> 1][1] = ss;
            }
        }
    }
    __syncthreads();
    // normalize -> Tt (staging LDS is dead) for BOTH paths
    #pragma unroll
    for (int i = 0; i < 4; i++) {
        #pragma unroll
        for (int r = 0; r < 4; r++) {
            int rl = rowbase + i * 16 + q * 4 + r;
            float S  = sstat[rl][0][0] + sstat[rl][1][0];
            float SS = sstat[rl][0][1] + sstat[rl][1][1];
            float mean = S * (1.f / 128.f);
            float var  = SS * (1.f / 128.f) - mean * mean;
            float inv  = rsqrtf(var + 1e-3f);
            #pragma unroll
            for (int j = 0; j < 4; j++) {
                int cl = colbase + j * 16 + c;
                float v = (acc[i][j][r] - mean) * inv * gcol[j] + Bcol[j];
                Tt[rl][cl] = f2b(v);
            }
        }
    }
    __syncthreads();
    if (which != 0) {
        // vectorized copy-out: Tt -> Z, u16x8 per lane (was 2B scalar stores)
        unsigned short* Zu = (unsigned short*)Z;
        #pragma unroll
        for (int i = 0; i < 8; i++) {
            int idx2 = i * 256 + t;          // 0..2047 = 128 rows x 16 chunks
            int row = idx2 >> 4, ch = (idx2 & 15) * 8;
            *(u16x8*)&Zu[(size_t)(r0 + row) * 1024 + n0 + ch] = *(const u16x8*)&Tt[row][ch];
        }
        return;
    }

    // ---- attn phase (verified R6/R7): basic = relu(Tt @ (Wbt*q)^T + bb)
    // B-operand fragments computed in-register from Wbt (bf16 [mid][d],
    // L2-hot 16 KB) and q (f32, 64 KB).
    const float* qrow = qws + b * 1024 + h * 128;
    f32x4 acc2[2][4];
    #pragma unroll
    for (int i = 0; i < 2; i++)
        #pragma unroll
        for (int j = 0; j < 4; j++) acc2[i][j] = fzero;
    #pragma unroll
    for (int s = 0; s < 4; s++) {
        bf16x8 af2[2], bfv[4];
        float qv[8];
        #pragma unroll
        for (int e = 0; e < 8; e++) qv[e] = qrow[s * 32 + q * 8 + e];
        #pragma unroll
        for (int i = 0; i < 2; i++)
            af2[i] = *(const bf16x8*)&Tt[w * 32 + i * 16 + c][s * 32 + q * 8];
        #pragma unroll
        for (int j = 0; j < 4; j++) {
            bf16x8 wv = *(const bf16x8*)&Wbt[(j * 16 + c) * 128 + s * 32 + q * 8];
            bf16x8 bv;
            #pragma unroll
            for (int e = 0; e < 8; e++)
                bv[e] = (short)f2b(b2f((unsigned short)wv[e]) * qv[e]);
            bfv[j] = bv;
        }
        #pragma unroll
        for (int i = 0; i < 2; i++)
            #pragma unroll
            for (int j = 0; j < 4; j++)
                acc2[i][j] = __builtin_amdgcn_mfma_f32_16x16x32_bf16(af2[i], bfv[j], acc2[i][j], 0, 0, 0);
    }

    float bbs[4], wl1s[4];
    #pragma unroll
    for (int j = 0; j < 4; j++) { bbs[j] = bbp[j * 16 + c]; wl1s[j] = Wl1[j * 16 + c]; }
    float bl1v = bl1[0];
    float pp[4] = {0.f, 0.f, 0.f, 0.f};
    #pragma unroll
    for (int i = 0; i < 2; i++) {
        #pragma unroll
        for (int r = 0; r < 4; r++) {
            int ml = w * 32 + i * 16 + q * 4 + r;
            float mv = masksh[ml];
            float lg = 0.f;
            #pragma unroll
            for (int j = 0; j < 4; j++) {
                float basic = fmaxf(acc2[i][j][r] + bbs[j], 0.f);
                lg += basic * wl1s[j];
                pp[j] += basic * mv;
            }
            lg += __shfl_xor(lg, 1); lg += __shfl_xor(lg, 2);
            lg += __shfl_xor(lg, 4); lg += __shfl_xor(lg, 8);
            if (c == 0)
                logits[((size_t)(b * 8 + h)) * 2048 + mloc + ml] = lg + bl1v;
        }
    }
    #pragma unroll
    for (int j = 0; j < 4; j++) {
        pp[j] += __shfl_xor(pp[j], 16);
        pp[j] += __shfl_xor(pp[j], 32);
    }
    if (lane < 16) {
        #pragma unroll
        for (int j = 0; j < 4; j++) poolred[w][j * 16 + c] = pp[j];
    }
    __syncthreads();
    if (t < 64) {
        float p = poolred[0][t] + poolred[1][t] + poolred[2][t] + poolred[3][t];
        poolpart[((size_t)((b * 8 + h) * 16 + mt)) * 64 + t] = p;
    }
}

// ---------------------------------------------------------------------------
// Kernel 3: FUSED softmax + pool + alpha_ch + v2 aggregation + output.
// grid (h=8, b=16), block 512 (8 waves: 2x latency hiding on the v2 read).
// ---------------------------------------------------------------------------
__global__ __launch_bounds__(512) void finalize_fused(
    const float* logits, const float* poolpart, fptr maskp,
    const __hip_bfloat16* v2buf, const float* v1ws,
    fptr Wl2, fptr bl2, float* out)
{
    __shared__ float alph[2048];
    __shared__ float red[8];
    __shared__ float redm[8];
    __shared__ float pools[64];
    __shared__ float ach[128];
    __shared__ float redl[8][128];
    int h = blockIdx.x, b = blockIdx.y;
    int t = threadIdx.x, lane = t & 63, wv = t >> 6;

    const float* lg = logits + (size_t)(b * 8 + h) * 2048;
    float msum_l = 0.f, mx_l = -1e30f;
    for (int i = t; i < 2048; i += 512) {
        float mv = maskp[b * 2048 + i];
        msum_l += mv;
        float v = (mv == 0.f) ? -1e9f : lg[i];
        alph[i] = v;
        mx_l = fmaxf(mx_l, v);
    }
    for (int mm = 32; mm > 0; mm >>= 1) {
        msum_l += __shfl_xor(msum_l, mm);
        mx_l = fmaxf(mx_l, __shfl_xor(mx_l, mm));
    }
    if (lane == 0) { red[wv] = msum_l; redm[wv] = mx_l; }
    __syncthreads();
    float msum = 0.f, mx = -1e30f;
    #pragma unroll
    for (int i = 0; i < 8; i++) { msum += red[i]; mx = fmaxf(mx, redm[i]); }

    float se = 0.f;
    for (int i = t; i < 2048; i += 512) {
        float e = __expf(alph[i] - mx);   // same thread wrote alph[i]
        alph[i] = e;
        se += e;
    }
    for (int mm = 32; mm > 0; mm >>= 1) se += __shfl_xor(se, mm);
    __syncthreads();
    if (lane == 0) red[wv] = se;
    __syncthreads();
    float S = 0.f;
    #pragma unroll
    for (int i = 0; i < 8; i++) S += red[i];
    float invS = 1.f / S;
    for (int i = t; i < 2048; i += 512) alph[i] *= invS;

    if (t < 64) {
        const float* pq = poolpart + ((size_t)(b * 8 + h) * 16) * 64 + t;
        float p = 0.f;
        for (int pt = 0; pt < 16; pt++) p += pq[pt * 64];
        pools[t] = p / msum;
    }
    __syncthreads();
    if (t < 128) {
        float s2 = bl2[t];
        for (int mid = 0; mid < 64; mid++) s2 += pools[mid] * Wl2[mid * 128 + t];
        ach[t] = 1.f / (1.f + __expf(-s2));
    }
    __syncthreads();

    // v2 aggregation over 2048 m: 8 waves x 4 m-rows per iter = 32 m/iter
    int mo = lane >> 4, d8 = (lane & 15) * 8;
    float acc[8] = {};
    for (int it = 0; it < 64; it++) {
        int m = it * 32 + wv * 4 + mo;
        bf16x8 v8 = *(const bf16x8*)&v2buf[((size_t)(b * 2048 + m)) * 1024 + h * 128 + d8];
        float a = alph[m];
        #pragma unroll
        for (int j = 0; j < 8; j++)
            acc[j] += a * b2f(((unsigned short*)&v8)[j]);
    }
    #pragma unroll
    for (int j = 0; j < 8; j++) {
        acc[j] += __shfl_xor(acc[j], 16);
        acc[j] += __shfl_xor(acc[j], 32);
    }
    if (lane < 16) {
        #pragma unroll
        for (int j = 0; j < 8; j++) redl[wv][d8 + j] = acc[j];
    }
    __syncthreads();
    if (t < 128) {
        float s = 0.f;
        #pragma unroll
        for (int i = 0; i < 8; i++) s += redl[i][t];
        out[b * 1024 + h * 128 + t] = v1ws[b * 1024 + h * 128 + t] * s * ach[t];
    }
}

// ---------------------------------------------------------------------------
extern "C" void kernel_launch(void* const* d_in, const int* in_sizes, int n_in,
                              void* d_out, int out_size, void* d_ws, size_t ws_size,
                              hipStream_t stream) {
    fptr query  = (fptr)d_in[0];
    fptr key    = (fptr)d_in[1];
    fptr maskp  = (fptr)d_in[2];
    fptr value1 = (fptr)d_in[3];
    fptr value2 = (fptr)d_in[4];
    fptr Wq = (fptr)d_in[5],  bq = (fptr)d_in[6],  gq = (fptr)d_in[7],  Bq = (fptr)d_in[8];
    fptr Wk = (fptr)d_in[9],  bk = (fptr)d_in[10], gk = (fptr)d_in[11], Bk = (fptr)d_in[12];
    fptr Wv1 = (fptr)d_in[13], bv1 = (fptr)d_in[14], gv1 = (fptr)d_in[15], Bv1 = (fptr)d_in[16];
    fptr Wv2 = (fptr)d_in[17], bv2 = (fptr)d_in[18], gv2 = (fptr)d_in[19], Bv2 = (fptr)d_in[20];
    fptr Wb = (fptr)d_in[21], bb = (fptr)d_in[22];
    fptr Wl1 = (fptr)d_in[23], bl1 = (fptr)d_in[24];
    fptr Wl2 = (fptr)d_in[25], bl2 = (fptr)d_in[26];

    const size_t MB = 1024 * 1024;
    char* w = (char*)d_ws;
    unsigned short* AbfK  = (unsigned short*)w;                      // 0..64 MB
    unsigned short* AbfV2 = (unsigned short*)(w + 64 * MB);          // 64..128 MB
    __hip_bfloat16* zV2   = (__hip_bfloat16*)(w + 128 * MB);         // 128..192 MB
    unsigned short* WtK   = (unsigned short*)(w + 192 * MB);         // 2 MB
    unsigned short* WtV2  = (unsigned short*)(w + 194 * MB);         // 2 MB
    unsigned short* Wbt   = (unsigned short*)(w + 196 * MB);         // 16 KB
    float* qws      = (float*)(w + 196 * MB + 65536 + 2 * MB);       // 64 KB
    float* v1ws     = qws + 16 * 1024;                               // 64 KB
    float* logits   = v1ws + 16 * 1024;                              // 1 MB
    float* poolpart = logits + 16 * 8 * 2048;                        // 512 KB (-> <200 MB total)
    float* out = (float*)d_out;

    hipLaunchKernelGGL(prep, dim3(4865), dim3(256), 0, stream,
                       key, value2, AbfK, AbfV2,
                       Wk, Wv2, WtK, WtV2, Wb, Wbt,
                       query, Wq, bq, gq, Bq, value1, Wv1, bv1, gv1, Bv1,
                       qws, v1ws);
    hipLaunchKernelGGL(gemm_fused, dim3(4096), dim3(256), 0, stream,
                       (bfp)AbfK, (bfp)WtK, bk, gk, Bk,
                       (bfp)AbfV2, (bfp)WtV2, bv2, gv2, Bv2,
                       (bfp)Wbt, qws, maskp, bb, Wl1, bl1, logits, poolpart, zV2);
    hipLaunchKernelGGL(finalize_fused, dim3(8, 16), dim3(512), 0, stream,
                       logits, poolpart, maskp, zV2, v1ws, Wl2, bl2, out);
}

// Round 4
// 529.889 us; speedup vs baseline: 1.1254x; 1.0677x over previous
//
#include <hip/hip_runtime.h>
#include <hip/hip_bf16.h>
#include <math.h>

typedef __attribute__((ext_vector_type(8))) short bf16x8;     // 8 bf16 = 4 VGPRs
typedef __attribute__((ext_vector_type(4))) float f32x4;      // MFMA accumulator
typedef __attribute__((ext_vector_type(8))) unsigned short u16x8;

typedef const float* fptr;
typedef const unsigned short* bfp;

__device__ inline float b2f(unsigned short u) {
    union { unsigned int i; float f; } v; v.i = ((unsigned int)u) << 16; return v.f;
}
__device__ inline unsigned short f2b(float x) {
    __hip_bfloat16 h = __float2bfloat16(x);
    return *(unsigned short*)&h;
}
// fast elu: __expf -> v_exp_f32 sequence; |err| ~1e-7 absolute near 0, fine for bf16-level outputs
__device__ inline float elu_f(float x) { return x > 0.f ? x : __expf(x) - 1.f; }

// async global->LDS, 16 bytes per lane; lds dest = wave-uniform base + lane*16
__device__ inline void load_lds16(const void* g, void* l) {
    __builtin_amdgcn_global_load_lds(
        (const __attribute__((address_space(1))) unsigned int*)g,
        (__attribute__((address_space(3))) unsigned int*)l, 16, 0, 0);
}

// ---------------------------------------------------------------------------
// Kernel 0 (PREP, R11: tiny now): grid 769.
// The key/value2 fp32->bf16 pre-conversion is GONE -- gemm_fused stages A
// directly from fp32 (in-register convert). prep keeps only:
//   0               Wbt = Wb^T (bf16 [mid][d])
//   [1, 257)        small in_proj (query->qws, value1->v1ws)
//   [257, 769)      transpose+convert Wk/Wv2 -> WtK/WtV2 (bf16 [n][k])
// ---------------------------------------------------------------------------
__global__ __launch_bounds__(256) void prep(
    fptr Wk, fptr Wv2, unsigned short* WtK, unsigned short* WtV2,
    fptr Wb, unsigned short* Wbt,
    fptr query, fptr Wq, fptr bq, fptr gq, fptr Bq,
    fptr value1, fptr Wv1, fptr bv1, fptr gv1, fptr Bv1,
    float* qws, float* v1ws)
{
    __shared__ __align__(16) char smem[16640];
    int blk = blockIdx.x, t = threadIdx.x;

    if (blk == 0) {                          // ---- Wbt
        unsigned short* tb = (unsigned short*)smem;
        for (int i = 0; i < 32; i++) {
            int idx = i * 256 + t;           // idx = d*64 + mid
            tb[(idx & 63) * 128 + (idx >> 6)] = f2b(Wb[idx]);
        }
        __syncthreads();
        for (int i = 0; i < 4; i++) {
            int o = (i * 256 + t) * 8;
            *(u16x8*)&Wbt[o] = *(const u16x8*)&tb[o];
        }
        return;
    }
    if (blk < 257) {                         // ---- small_proj
        float* xs = (float*)smem;                      // 1024 f32
        float (*part)[128] = (float (*)[128])(smem + 4096);
        float (*r4)[2] = (float (*)[2])(smem + 4096 + 1024);
        int idx = blk - 1;
        int hgrp = idx & 7;
        int row  = (idx >> 3) & 15;
        int which = idx >> 7;
        fptr x  = which ? value1 : query;
        fptr W  = which ? Wv1 : Wq;
        fptr bi = which ? bv1 : bq;
        fptr g  = which ? gv1 : gq;
        fptr be = which ? Bv1 : Bq;
        float* outp = which ? v1ws : qws;
        int lane = t & 63, wv = t >> 6;
        for (int i = t; i < 1024; i += 256) xs[i] = x[row * 1024 + i];
        __syncthreads();
        int cl = t & 127, kh = t >> 7;
        int col = hgrp * 128 + cl;
        float acc = 0.f;
        const float* wp = W + (size_t)(kh * 512) * 1024 + col;
        for (int k = 0; k < 512; k++) acc += xs[kh * 512 + k] * wp[(size_t)k * 1024];
        part[kh][cl] = acc;
        __syncthreads();
        float e = 0.f;
        if (t < 128) e = elu_f(part[0][t] + part[1][t] + bi[col]);
        float s = e, ss = e * e;
        for (int m = 32; m > 0; m >>= 1) { s += __shfl_xor(s, m); ss += __shfl_xor(ss, m); }
        if (lane == 0) { r4[wv][0] = s; r4[wv][1] = ss; }
        __syncthreads();
        float S  = r4[0][0] + r4[1][0] + r4[2][0] + r4[3][0];
        float SS = r4[0][1] + r4[1][1] + r4[2][1] + r4[3][1];
        float mean = S * (1.f / 128.f);
        float var  = SS * (1.f / 128.f) - mean * mean;
        float inv  = rsqrtf(var + 1e-3f);
        if (t < 128) outp[row * 1024 + col] = (e - mean) * inv * g[col] + be[col];
        return;
    }
    {                                        // ---- convert_w (transpose)
        float (*tl)[65] = (float (*)[65])smem;
        int idx = blk - 257;
        fptr W = (idx >> 8) ? Wv2 : Wk;
        unsigned short* Wt = (idx >> 8) ? WtV2 : WtK;
        int k0 = ((idx >> 4) & 15) * 64, n0 = (idx & 15) * 64;
        #pragma unroll
        for (int i = 0; i < 16; i++) {
            int kl = i * 4 + (t >> 6), nl = t & 63;
            tl[kl][nl] = W[(size_t)(k0 + kl) * 1024 + n0 + nl];
        }
        __syncthreads();
        // vectorized write: 8 consecutive k per thread -> u16x8 (16B/lane)
        #pragma unroll
        for (int i = 0; i < 2; i++) {
            int nl = i * 32 + (t >> 3), kl8 = (t & 7) * 8;
            u16x8 o;
            #pragma unroll
            for (int e = 0; e < 8; e++) o[e] = f2b(tl[kl8 + e][nl]);
            *(u16x8*)&Wt[(size_t)(n0 + nl) * 1024 + k0 + kl8] = o;
        }
    }
}

// ---------------------------------------------------------------------------
// Kernel 2: BOTH big GEMMs in one dispatch. grid(4096), block 256.
// R8 A-LOCALITY DECODE (verified: FETCH 541->115 MB): xcd = bid & 7,
// seq = bid >> 3, grp = seq >> 3, h = seq & 7, which = grp >> 5,
// rowtile = xcd * 32 + (grp & 31). 8 h-blocks sharing an A panel run
// back-to-back on one XCD -> panel L2-resident, HBM-fetched once.
// R11: A staged DIRECTLY FROM FP32 (key/value2) with in-register f2b
// convert + ds_write_b128 -- same LDS image as the old global_load_lds
// path; B keeps global_load_lds. This deletes prep's 384 MB convert pass
// and the device-wide convert->gemm dependency. A fp32 panels (512 KB)
// are L2-served for the 8 h re-reads (XCD decode), so FETCH ~= 256 MB + W.
// R9/R10: __launch_bounds__(256,4) (verified: occupancy 40%, -18 us);
// which==1 Z-write routed through Tt LDS then stored u16x8.
// ---------------------------------------------------------------------------
__global__ __launch_bounds__(256, 4) void gemm_fused(
    fptr AKf, bfp WtK, fptr bkp, fptr gkp, fptr Bkp,
    fptr AVf, bfp WtV, fptr bvp, fptr gvp, fptr Bvp,
    bfp Wbt, const float* qws, fptr maskp, fptr bbp, fptr Wl1, fptr bl1,
    float* logits, float* poolpart, __hip_bfloat16* Z)
{
    __shared__ __align__(16) unsigned short pool[17408];
    unsigned short (*As)[128][32] = (unsigned short (*)[128][32])pool;
    unsigned short (*Bs)[128][32] = (unsigned short (*)[128][32])(pool + 8192);
    unsigned short (*Tt)[136]     = (unsigned short (*)[136])pool;
    __shared__ float sstat[128][2][2];
    __shared__ float masksh[128];
    __shared__ float poolred[4][64];

    int bid = blockIdx.x;
    int xcd = bid & 7;
    int seq = bid >> 3;              // per-XCD issue order 0..511
    int grp = seq >> 3;              // 0..63: A-panel group
    int h   = seq & 7;               // all 8 h of a panel adjacent on one XCD
    int which = grp >> 5;            // K-gemm phase, then V2-gemm phase
    int rowtile = xcd * 32 + (grp & 31);   // 0..255

    int r0 = rowtile * 128;          // global row (b*2048 + mloc)
    int n0 = h * 128;
    int b  = r0 >> 11;
    int mloc = r0 & 2047;
    int mt = rowtile & 15;
    int t = threadIdx.x, lane = t & 63, w = t >> 6;
    int c = lane & 15, q = lane >> 4;
    int rowbase = (w & 1) * 64, colbase = (w >> 1) * 64;

    fptr Af   = which ? AVf : AKf;
    bfp Wt    = which ? WtV : WtK;
    fptr bias = which ? bvp : bkp;
    fptr g    = which ? gvp : gkp;
    fptr be   = which ? Bvp : Bkp;

    if (which == 0 && t < 128) masksh[t] = maskp[r0 + t];

    f32x4 acc[4][4];
    const f32x4 fzero = {0.f, 0.f, 0.f, 0.f};
    #pragma unroll
    for (int i = 0; i < 4; i++)
        #pragma unroll
        for (int j = 0; j < 4; j++) acc[i][j] = fzero;

    int srow = lane >> 2;            // 0..15 within a 16-row issue
    int sseg = (lane & 3) * 8;       // k offset (8 elems = 16B bf16 / 32B f32)
    const float* agf = Af + (size_t)(r0 + w * 32 + srow) * 1024 + sseg;
    const unsigned short* bg = Wt + (size_t)(n0 + w * 32 + srow) * 1024 + sseg;

    for (int k0 = 0; k0 < 1024; k0 += 64) {
        // B: async global->LDS (no VGPR round-trip)
        load_lds16(bg + k0,                  &Bs[0][w * 32][0]);
        load_lds16(bg + k0 + 16 * 1024,      &Bs[0][w * 32 + 16][0]);
        load_lds16(bg + k0 + 32,             &Bs[1][w * 32][0]);
        load_lds16(bg + k0 + 32 + 16 * 1024, &Bs[1][w * 32 + 16][0]);
        // A: fp32 -> bf16 reg-staging, same LDS image as the old path.
        // chunk ch: panel = ch>>1, row block = (ch&1)*16, k-off = (ch>>1)*32
        #pragma unroll
        for (int ch = 0; ch < 4; ch++) {
            const float* src = agf + k0 + (ch & 1) * 16 * 1024 + (ch >> 1) * 32;
            float4 f0 = *(const float4*)src;
            float4 f1 = *(const float4*)(src + 4);
            u16x8 hv = { f2b(f0.x), f2b(f0.y), f2b(f0.z), f2b(f0.w),
                         f2b(f1.x), f2b(f1.y), f2b(f1.z), f2b(f1.w) };
            *(u16x8*)&As[ch >> 1][w * 32 + (ch & 1) * 16 + srow][sseg] = hv;
        }
        __syncthreads();
        #pragma unroll
        for (int p = 0; p < 2; p++) {
            bf16x8 af[4], bfv[4];
            #pragma unroll
            for (int i = 0; i < 4; i++) af[i]  = *(const bf16x8*)&As[p][rowbase + i * 16 + c][q * 8];
            #pragma unroll
            for (int j = 0; j < 4; j++) bfv[j] = *(const bf16x8*)&Bs[p][colbase + j * 16 + c][q * 8];
            #pragma unroll
            for (int i = 0; i < 4; i++)
                #pragma unroll
                for (int j = 0; j < 4; j++)
                    acc[i][j] = __builtin_amdgcn_mfma_f32_16x16x32_bf16(af[i], bfv[j], acc[i][j], 0, 0, 0);
        }
        __syncthreads();
    }

    // ---- bias + elu + groupnorm stats (verified epilogue)
    float bcol[4], gcol[4], Bcol[4];
    #pragma unroll
    for (int j = 0; j < 4; j++) {
        int cg = n0 + colbase + j * 16 + c;
        bcol[j] = bias[cg]; gcol[j] = g[cg]; Bcol[j] = be[cg];
    }
    #pragma unroll
    for (int i = 0; i < 4; i++)
        #pragma unroll
        for (int j = 0; j < 4; j++)
            #pragma unroll
            for (int r = 0; r < 4; r++)
                acc[i][j][r] = elu_f(acc[i][j][r] + bcol[j]);
    #pragma unroll
    for (int i = 0; i < 4; i++) {
        #pragma unroll
        for (int r = 0; r < 4; r++) {
            float s  = acc[i][0][r] + acc[i][1][r] + acc[i][2][r] + acc[i][3][r];
            float ss = acc[i][0][r] * acc[i][0][r] + acc[i][1][r] * acc[i][1][r]
                     + acc[i][2][r] * acc[i][2][r] + acc[i][3][r] * acc[i][3][r];
            for (int m = 1; m < 16; m <<= 1) { s += __shfl_xor(s, m); ss += __shfl_xor(ss, m); }
            if (c == 0) {
                int rl = rowbase + i * 16 + q * 4 + r;
                sstat[rl][w >> 1][0] = s;
                sstat[rl][w >> 1][1] = ss;
            }
        }
    }
    __syncthreads();
    // normalize -> Tt (staging LDS is dead) for BOTH paths
    #pragma unroll
    for (int i = 0; i < 4; i++) {
        #pragma unroll
        for (int r = 0; r < 4; r++) {
            int rl = rowbase + i * 16 + q * 4 + r;
            float S  = sstat[rl][0][0] + sstat[rl][1][0];
            float SS = sstat[rl][0][1] + sstat[rl][1][1];
            float mean = S * (1.f / 128.f);
            float var  = SS * (1.f / 128.f) - mean * mean;
            float inv  = rsqrtf(var + 1e-3f);
            #pragma unroll
            for (int j = 0; j < 4; j++) {
                int cl = colbase + j * 16 + c;
                float v = (acc[i][j][r] - mean) * inv * gcol[j] + Bcol[j];
                Tt[rl][cl] = f2b(v);
            }
        }
    }
    __syncthreads();
    if (which != 0) {
        // vectorized copy-out: Tt -> Z, u16x8 per lane
        unsigned short* Zu = (unsigned short*)Z;
        #pragma unroll
        for (int i = 0; i < 8; i++) {
            int idx2 = i * 256 + t;          // 0..2047 = 128 rows x 16 chunks
            int row = idx2 >> 4, ch = (idx2 & 15) * 8;
            *(u16x8*)&Zu[(size_t)(r0 + row) * 1024 + n0 + ch] = *(const u16x8*)&Tt[row][ch];
        }
        return;
    }

    // ---- attn phase (verified R6/R7): basic = relu(Tt @ (Wbt*q)^T + bb)
    // B-operand fragments computed in-register from Wbt (bf16 [mid][d],
    // L2-hot 16 KB) and q (f32, 64 KB).
    const float* qrow = qws + b * 1024 + h * 128;
    f32x4 acc2[2][4];
    #pragma unroll
    for (int i = 0; i < 2; i++)
        #pragma unroll
        for (int j = 0; j < 4; j++) acc2[i][j] = fzero;
    #pragma unroll
    for (int s = 0; s < 4; s++) {
        bf16x8 af2[2], bfv[4];
        float qv[8];
        #pragma unroll
        for (int e = 0; e < 8; e++) qv[e] = qrow[s * 32 + q * 8 + e];
        #pragma unroll
        for (int i = 0; i < 2; i++)
            af2[i] = *(const bf16x8*)&Tt[w * 32 + i * 16 + c][s * 32 + q * 8];
        #pragma unroll
        for (int j = 0; j < 4; j++) {
            bf16x8 wv = *(const bf16x8*)&Wbt[(j * 16 + c) * 128 + s * 32 + q * 8];
            bf16x8 bv;
            #pragma unroll
            for (int e = 0; e < 8; e++)
                bv[e] = (short)f2b(b2f((unsigned short)wv[e]) * qv[e]);
            bfv[j] = bv;
        }
        #pragma unroll
        for (int i = 0; i < 2; i++)
            #pragma unroll
            for (int j = 0; j < 4; j++)
                acc2[i][j] = __builtin_amdgcn_mfma_f32_16x16x32_bf16(af2[i], bfv[j], acc2[i][j], 0, 0, 0);
    }

    float bbs[4], wl1s[4];
    #pragma unroll
    for (int j = 0; j < 4; j++) { bbs[j] = bbp[j * 16 + c]; wl1s[j] = Wl1[j * 16 + c]; }
    float bl1v = bl1[0];
    float pp[4] = {0.f, 0.f, 0.f, 0.f};
    #pragma unroll
    for (int i = 0; i < 2; i++) {
        #pragma unroll
        for (int r = 0; r < 4; r++) {
            int ml = w * 32 + i * 16 + q * 4 + r;
            float mv = masksh[ml];
            float lg = 0.f;
            #pragma unroll
            for (int j = 0; j < 4; j++) {
                float basic = fmaxf(acc2[i][j][r] + bbs[j], 0.f);
                lg += basic * wl1s[j];
                pp[j] += basic * mv;
            }
            lg += __shfl_xor(lg, 1); lg += __shfl_xor(lg, 2);
            lg += __shfl_xor(lg, 4); lg += __shfl_xor(lg, 8);
            if (c == 0)
                logits[((size_t)(b * 8 + h)) * 2048 + mloc + ml] = lg + bl1v;
        }
    }
    #pragma unroll
    for (int j = 0; j < 4; j++) {
        pp[j] += __shfl_xor(pp[j], 16);
        pp[j] += __shfl_xor(pp[j], 32);
    }
    if (lane < 16) {
        #pragma unroll
        for (int j = 0; j < 4; j++) poolred[w][j * 16 + c] = pp[j];
    }
    __syncthreads();
    if (t < 64) {
        float p = poolred[0][t] + poolred[1][t] + poolred[2][t] + poolred[3][t];
        poolpart[((size_t)((b * 8 + h) * 16 + mt)) * 64 + t] = p;
    }
}

// ---------------------------------------------------------------------------
// Kernel 3: FUSED softmax + pool + alpha_ch + v2 aggregation + output.
// grid (h=8, b=16), block 512 (8 waves: 2x latency hiding on the v2 read).
// ---------------------------------------------------------------------------
__global__ __launch_bounds__(512) void finalize_fused(
    const float* logits, const float* poolpart, fptr maskp,
    const __hip_bfloat16* v2buf, const float* v1ws,
    fptr Wl2, fptr bl2, float* out)
{
    __shared__ float alph[2048];
    __shared__ float red[8];
    __shared__ float redm[8];
    __shared__ float pools[64];
    __shared__ float ach[128];
    __shared__ float redl[8][128];
    int h = blockIdx.x, b = blockIdx.y;
    int t = threadIdx.x, lane = t & 63, wv = t >> 6;

    const float* lg = logits + (size_t)(b * 8 + h) * 2048;
    float msum_l = 0.f, mx_l = -1e30f;
    for (int i = t; i < 2048; i += 512) {
        float mv = maskp[b * 2048 + i];
        msum_l += mv;
        float v = (mv == 0.f) ? -1e9f : lg[i];
        alph[i] = v;
        mx_l = fmaxf(mx_l, v);
    }
    for (int mm = 32; mm > 0; mm >>= 1) {
        msum_l += __shfl_xor(msum_l, mm);
        mx_l = fmaxf(mx_l, __shfl_xor(mx_l, mm));
    }
    if (lane == 0) { red[wv] = msum_l; redm[wv] = mx_l; }
    __syncthreads();
    float msum = 0.f, mx = -1e30f;
    #pragma unroll
    for (int i = 0; i < 8; i++) { msum += red[i]; mx = fmaxf(mx, redm[i]); }

    float se = 0.f;
    for (int i = t; i < 2048; i += 512) {
        float e = __expf(alph[i] - mx);   // same thread wrote alph[i]
        alph[i] = e;
        se += e;
    }
    for (int mm = 32; mm > 0; mm >>= 1) se += __shfl_xor(se, mm);
    __syncthreads();
    if (lane == 0) red[wv] = se;
    __syncthreads();
    float S = 0.f;
    #pragma unroll
    for (int i = 0; i < 8; i++) S += red[i];
    float invS = 1.f / S;
    for (int i = t; i < 2048; i += 512) alph[i] *= invS;

    if (t < 64) {
        const float* pq = poolpart + ((size_t)(b * 8 + h) * 16) * 64 + t;
        float p = 0.f;
        for (int pt = 0; pt < 16; pt++) p += pq[pt * 64];
        pools[t] = p / msum;
    }
    __syncthreads();
    if (t < 128) {
        float s2 = bl2[t];
        for (int mid = 0; mid < 64; mid++) s2 += pools[mid] * Wl2[mid * 128 + t];
        ach[t] = 1.f / (1.f + __expf(-s2));
    }
    __syncthreads();

    // v2 aggregation over 2048 m: 8 waves x 4 m-rows per iter = 32 m/iter
    int mo = lane >> 4, d8 = (lane & 15) * 8;
    float acc[8] = {};
    for (int it = 0; it < 64; it++) {
        int m = it * 32 + wv * 4 + mo;
        bf16x8 v8 = *(const bf16x8*)&v2buf[((size_t)(b * 2048 + m)) * 1024 + h * 128 + d8];
        float a = alph[m];
        #pragma unroll
        for (int j = 0; j < 8; j++)
            acc[j] += a * b2f(((unsigned short*)&v8)[j]);
    }
    #pragma unroll
    for (int j = 0; j < 8; j++) {
        acc[j] += __shfl_xor(acc[j], 16);
        acc[j] += __shfl_xor(acc[j], 32);
    }
    if (lane < 16) {
        #pragma unroll
        for (int j = 0; j < 8; j++) redl[wv][d8 + j] = acc[j];
    }
    __syncthreads();
    if (t < 128) {
        float s = 0.f;
        #pragma unroll
        for (int i = 0; i < 8; i++) s += redl[i][t];
        out[b * 1024 + h * 128 + t] = v1ws[b * 1024 + h * 128 + t] * s * ach[t];
    }
}

// ---------------------------------------------------------------------------
extern "C" void kernel_launch(void* const* d_in, const int* in_sizes, int n_in,
                              void* d_out, int out_size, void* d_ws, size_t ws_size,
                              hipStream_t stream) {
    fptr query  = (fptr)d_in[0];
    fptr key    = (fptr)d_in[1];
    fptr maskp  = (fptr)d_in[2];
    fptr value1 = (fptr)d_in[3];
    fptr value2 = (fptr)d_in[4];
    fptr Wq = (fptr)d_in[5],  bq = (fptr)d_in[6],  gq = (fptr)d_in[7],  Bq = (fptr)d_in[8];
    fptr Wk = (fptr)d_in[9],  bk = (fptr)d_in[10], gk = (fptr)d_in[11], Bk = (fptr)d_in[12];
    fptr Wv1 = (fptr)d_in[13], bv1 = (fptr)d_in[14], gv1 = (fptr)d_in[15], Bv1 = (fptr)d_in[16];
    fptr Wv2 = (fptr)d_in[17], bv2 = (fptr)d_in[18], gv2 = (fptr)d_in[19], Bv2 = (fptr)d_in[20];
    fptr Wb = (fptr)d_in[21], bb = (fptr)d_in[22];
    fptr Wl1 = (fptr)d_in[23], bl1 = (fptr)d_in[24];
    fptr Wl2 = (fptr)d_in[25], bl2 = (fptr)d_in[26];

    const size_t MB = 1024 * 1024;
    char* w = (char*)d_ws;
    __hip_bfloat16* zV2   = (__hip_bfloat16*)w;                      // 0..64 MB
    unsigned short* WtK   = (unsigned short*)(w + 64 * MB);          // 2 MB
    unsigned short* WtV2  = (unsigned short*)(w + 66 * MB);          // 2 MB
    unsigned short* Wbt   = (unsigned short*)(w + 68 * MB);          // 16 KB
    float* qws      = (float*)(w + 68 * MB + 65536);                 // 64 KB
    float* v1ws     = qws + 16 * 1024;                               // 64 KB
    float* logits   = v1ws + 16 * 1024;                              // 1 MB
    float* poolpart = logits + 16 * 8 * 2048;                        // 512 KB
    float* out = (float*)d_out;

    hipLaunchKernelGGL(prep, dim3(769), dim3(256), 0, stream,
                       Wk, Wv2, WtK, WtV2, Wb, Wbt,
                       query, Wq, bq, gq, Bq, value1, Wv1, bv1, gv1, Bv1,
                       qws, v1ws);
    hipLaunchKernelGGL(gemm_fused, dim3(4096), dim3(256), 0, stream,
                       key, (bfp)WtK, bk, gk, Bk,
                       value2, (bfp)WtV2, bv2, gv2, Bv2,
                       (bfp)Wbt, qws, maskp, bb, Wl1, bl1, logits, poolpart, zV2);
    hipLaunchKernelGGL(finalize_fused, dim3(8, 16), dim3(512), 0, stream,
                       logits, poolpart, maskp, zV2, v1ws, Wl2, bl2, out);
}